// Round 7
// baseline (238.451 us; speedup 1.0000x reference)
//
#include <hip/hip_runtime.h>
#include <hip/hip_bf16.h>

#define D 64   // D_IN == D_OUT == 64
#define M44 ((1ULL << 44) - 1)

// ---------------------------------------------------------------------------
// k_count: ONE 64-bit atomic per edge. high 20 bits = count, low 44 =
// fixed-point(2^-32) sum of ew. Returned old -> exact within-row rank free.
// MEASURED WALL: ~21.5G RMW/s device atomic throughput (r5/r6 sharding test
// proved it's NOT line contention) -> 1M edges ~= 46.5 us. Do not re-try
// sharding.
__global__ __launch_bounds__(256) void k_count(const int* __restrict__ rowi,
                                               const float* __restrict__ ew,
                                               unsigned long long* __restrict__ packed,
                                               int* __restrict__ rank, int nE) {
    int e = blockIdx.x * 256 + threadIdx.x;
    if (e < nE) {
        unsigned long long fx = (unsigned long long)((double)ew[e] * 4294967296.0);
        unsigned long long old = atomicAdd(&packed[rowi[e]], (1ULL << 44) | fx);
        rank[e] = (int)(old >> 44);
    }
}

// k_scan: deg=1+sum(fx) (self-loop), dis=rsqrt(deg); CSR segment starts via
// wave-scan -> one global atomic per wave.
__global__ __launch_bounds__(256) void k_scan(const unsigned long long* __restrict__ packed,
                                              float* __restrict__ dis,
                                              int* __restrict__ cnt,
                                              int* __restrict__ start,
                                              int* __restrict__ counter, int n) {
    int i = blockIdx.x * 256 + threadIdx.x;
    int lane = threadIdx.x & 63;
    unsigned long long p = (i < n) ? packed[i] : 0ULL;
    int c = (int)(p >> 44);
    if (i < n) {
        float dg = (float)(1.0 + (double)(p & M44) * (1.0 / 4294967296.0));
        dis[i] = rsqrtf(dg);
        cnt[i] = c;
    }
    int incl = c;
#pragma unroll
    for (int o = 1; o < 64; o <<= 1) {
        int t = __shfl_up(incl, o, 64);
        if (lane >= o) incl += t;
    }
    int total = __shfl(incl, 63, 64);
    int base = 0;
    if (lane == 0) base = atomicAdd(counter, total);
    base = __shfl(base, 0, 64);
    if (i < n) start[i] = base + incl - c;
}

// k_place: atomic-free placement at start[row]+rank. COMPRESSED 4B record:
// (col<<15) | fixed15(ew*dis[col]).  w in (0,1); 15-bit fixed point abs err
// <= 2^-16 -> ~5e-4 on output (threshold 0.1). Halves scatter-write and
// gather edge-stream vs int2. dis[col] random load is L2-resident (400 KB).
__global__ __launch_bounds__(256) void k_place(const int* __restrict__ rowi,
                                               const int* __restrict__ coli,
                                               const float* __restrict__ ew,
                                               const float* __restrict__ dis,
                                               const int* __restrict__ start,
                                               const int* __restrict__ rank,
                                               unsigned int* __restrict__ scw, int nE) {
    int e = blockIdx.x * 256 + threadIdx.x;
    if (e < nE) {
        int c = coli[e];
        float w = ew[e] * dis[c];
        int q = (int)(w * 32768.0f + 0.5f);
        if (q > 32767) q = 32767;
        scw[start[rowi[e]] + rank[e]] = ((unsigned int)c << 15) | (unsigned int)q;
    }
}

// k_gather_gemm (FUSED): block owns 64 output rows. Phase 1: 16 lane-groups
// gather 4 nodes each (dis_i*(dis_i*x_i + sum w*x[col])) straight into the
// swizzled Ast LDS tile -- no agg round-trip through HBM (saves 51 MB + a
// launch). Phase 2: round-5 proven 4x4-register-tile GEMM out of LDS.
// Swizzle keeps all LDS ops at bank floor; launch_bounds(256,4) caps VGPR
// (round-4 lesson: no giant unrolled shuffle lattices).
__global__ __launch_bounds__(256, 4) void k_gather_gemm(const float* __restrict__ x,
                                                        const float* __restrict__ dis,
                                                        const int* __restrict__ start,
                                                        const int* __restrict__ cnt,
                                                        const unsigned int* __restrict__ scw,
                                                        const float* __restrict__ W,
                                                        const float* __restrict__ bias,
                                                        float* __restrict__ out, int n) {
    __shared__ float Ast[D * D];   // 16 KB, swizzled float4 slots
    __shared__ float Bs[D * D];    // 16 KB
    float4* Ast4 = (float4*)Ast;
    int tid = threadIdx.x;
    int r0 = blockIdx.x * 64;

    // stage W (transpose, swizzled slot (gq+k)&15)
    const float4* W4 = (const float4*)W;
#pragma unroll
    for (int v = 0; v < 4; ++v) {
        int idx = tid + v * 256;
        int a  = idx >> 4;                // out-ch o
        int kc = idx & 15;
        float4 wv = W4[idx];
        int gq = a >> 2, oo = a & 3;
        { int k = 4 * kc + 0; Bs[k * 64 + 4 * ((gq + k) & 15) + oo] = wv.x; }
        { int k = 4 * kc + 1; Bs[k * 64 + 4 * ((gq + k) & 15) + oo] = wv.y; }
        { int k = 4 * kc + 2; Bs[k * 64 + 4 * ((gq + k) & 15) + oo] = wv.z; }
        { int k = 4 * kc + 3; Bs[k * 64 + 4 * ((gq + k) & 15) + oo] = wv.w; }
    }

    // gather phase: group grp handles rows r0+4*grp .. +3, lane j = k-chunk
    int j   = tid & 15;
    int grp = tid >> 4;
    const float4* x4 = (const float4*)x;
#pragma unroll
    for (int m = 0; m < 4; ++m) {
        int i = r0 + 4 * grp + m;
        float4 acc = make_float4(0.f, 0.f, 0.f, 0.f);
        if (i < n) {
            int s = start[i];
            int e_end = s + cnt[i];
            for (int e = s; e < e_end; e += 16) {
                int idx = e + j;
                unsigned int v = 0u;
                if (idx < e_end) v = scw[idx];
                int mm = e_end - e; if (mm > 16) mm = 16;
#pragma unroll
                for (int t = 0; t < 16; ++t) {
                    if (t < mm) {
                        unsigned int rec = (unsigned int)__shfl((int)v, t, 16);
                        int col = (int)(rec >> 15);
                        float w = (float)(rec & 32767u) * (1.0f / 32768.0f);
                        float4 xv = x4[col * 16 + j];
                        acc.x += w * xv.x; acc.y += w * xv.y;
                        acc.z += w * xv.z; acc.w += w * xv.w;
                    }
                }
            }
            float di = dis[i];
            float4 xi = x4[i * 16 + j];
            acc.x = di * (di * xi.x + acc.x);
            acc.y = di * (di * xi.y + acc.y);
            acc.z = di * (di * xi.z + acc.z);
            acc.w = di * (di * xi.w + acc.w);
        }
        int a = 4 * grp + m;
        Ast4[a * 16 + ((j + (a >> 2)) & 15)] = acc;
    }
    __syncthreads();

    // GEMM phase (round-5 proven)
    int ty = tid >> 4;
    int tx = tid & 15;
    float acc[4][4];
#pragma unroll
    for (int m = 0; m < 4; ++m)
#pragma unroll
        for (int q = 0; q < 4; ++q) acc[m][q] = 0.f;

#pragma unroll 4
    for (int kc = 0; kc < 16; ++kc) {
        float4 a4[4], b4[4];
#pragma unroll
        for (int m = 0; m < 4; ++m)
            a4[m] = Ast4[(4 * ty + m) * 16 + ((kc + ty) & 15)];
#pragma unroll
        for (int i = 0; i < 4; ++i) {
            int k = 4 * kc + i;
            b4[i] = *(const float4*)&Bs[k * 64 + 4 * ((tx + k) & 15)];
        }
#pragma unroll
        for (int m = 0; m < 4; ++m) {
            acc[m][0] += a4[m].x * b4[0].x + a4[m].y * b4[1].x + a4[m].z * b4[2].x + a4[m].w * b4[3].x;
            acc[m][1] += a4[m].x * b4[0].y + a4[m].y * b4[1].y + a4[m].z * b4[2].y + a4[m].w * b4[3].y;
            acc[m][2] += a4[m].x * b4[0].z + a4[m].y * b4[1].z + a4[m].z * b4[2].z + a4[m].w * b4[3].z;
            acc[m][3] += a4[m].x * b4[0].w + a4[m].y * b4[1].w + a4[m].z * b4[2].w + a4[m].w * b4[3].w;
        }
    }

    float4 bv = ((const float4*)bias)[tx];
    float4* out4 = (float4*)out;
#pragma unroll
    for (int m = 0; m < 4; ++m) {
        int r = r0 + 4 * ty + m;
        if (r < n) {
            float4 o;
            o.x = acc[m][0] + bv.x; o.y = acc[m][1] + bv.y;
            o.z = acc[m][2] + bv.z; o.w = acc[m][3] + bv.w;
            out4[r * 16 + tx] = o;
        }
    }
}

extern "C" void kernel_launch(void* const* d_in, const int* in_sizes, int n_in,
                              void* d_out, int out_size, void* d_ws, size_t ws_size,
                              hipStream_t stream) {
    const float* x    = (const float*)d_in[0];
    const int*   ei   = (const int*)d_in[1];   // [2*E] flat: rows then cols
    const float* ew   = (const float*)d_in[2];
    const float* W    = (const float*)d_in[3];
    const float* bias = (const float*)d_in[4];
    float* out = (float*)d_out;

    int n  = in_sizes[0] / D;   // 100000
    int nE = in_sizes[2];       // 1000000
    const int* rowi = ei;
    const int* coli = ei + nE;

    // workspace (~10 MB): packed (n*8) | counter | rank | scw | dis | cnt | start
    char* w = (char*)d_ws;
    unsigned long long* packed = (unsigned long long*)w; w += (size_t)n * 8;
    int* counter = (int*)w;                              w += 64;   // same memset as packed
    int* rank    = (int*)w;                              w += (size_t)nE * 4;
    unsigned int* scw = (unsigned int*)w;                w += (size_t)nE * 4;
    float* dis   = (float*)w;                            w += (size_t)n * 4;
    int*   cnt   = (int*)w;                              w += (size_t)n * 4;
    int*   start = (int*)w;

    int gn = (n + 255) / 256;
    int gE = (nE + 255) / 256;

    hipMemsetAsync(packed, 0, (size_t)n * 8 + 64, stream);   // packed + counter
    k_count<<<gE, 256, 0, stream>>>(rowi, ew, packed, rank, nE);
    k_scan <<<gn, 256, 0, stream>>>(packed, dis, cnt, start, counter, n);
    k_place<<<gE, 256, 0, stream>>>(rowi, coli, ew, dis, start, rank, scw, nE);
    k_gather_gemm<<<(n + 63) / 64, 256, 0, stream>>>(x, dis, start, cnt, scw, W, bias, out, n);
}

// Round 8
// 224.468 us; speedup vs baseline: 1.0623x; 1.0623x over previous
//
#include <hip/hip_runtime.h>
#include <hip/hip_bf16.h>

#define D 64            // D_IN == D_OUT == 64
#define K 32            // static slots per node; deg ~ Poisson(10), P(>32)~1e-8
#define M44 ((1ULL << 44) - 1)
#define SPILLCAP 65536

// ---------------------------------------------------------------------------
// k_build: SINGLE-PASS CSR. Per edge: one packed 64-bit atomic (count in high
// 20 bits -> rank; fixed-point ew sum in low 44 -> exact deg) + one direct 4B
// record store at slots[row*K + rank]. Replaces r5/r7's count+scan+place
// (~120 us pipeline) with one kernel. Record: (col<<15) | q15(ew); col<2^17 ok,
// ew in (0,1) -> abs err <= 1.5e-5.  Rank >= K (statistically ~never) -> spill.
// MEASURED WALL (r5/r6): ~21.5G RMW/s device atomics; sharding doesn't help.
__global__ __launch_bounds__(256) void k_build(const int* __restrict__ rowi,
                                               const int* __restrict__ coli,
                                               const float* __restrict__ ew,
                                               unsigned long long* __restrict__ packed,
                                               unsigned int* __restrict__ slots,
                                               int4* __restrict__ spill,
                                               int* __restrict__ spillCnt, int nE) {
    int e = blockIdx.x * 256 + threadIdx.x;
    if (e >= nE) return;
    int r = rowi[e];
    int c = coli[e];
    float w = ew[e];
    unsigned long long fx = (unsigned long long)((double)w * 4294967296.0);
    unsigned long long old = atomicAdd(&packed[r], (1ULL << 44) | fx);
    int rank = (int)(old >> 44);
    if (rank < K) {
        int q = (int)(w * 32768.0f + 0.5f);
        if (q > 32767) q = 32767;
        slots[r * K + rank] = ((unsigned int)c << 15) | (unsigned int)q;
    } else {
        int p = atomicAdd(spillCnt, 1);
        if (p < SPILLCAP) spill[p] = make_int4(r, c, __float_as_int(w), 0);
    }
}

// k_dis: dis[i] = rsqrt(1 + sum_ew) exact from fixed-point; cnt = min(count,K).
// Pure streaming, ~2 us.
__global__ __launch_bounds__(256) void k_dis(const unsigned long long* __restrict__ packed,
                                             float* __restrict__ dis,
                                             int* __restrict__ cnt, int n) {
    int i = blockIdx.x * 256 + threadIdx.x;
    if (i >= n) return;
    unsigned long long p = packed[i];
    int c = (int)(p >> 44);
    if (c > K) c = K;
    float dg = (float)(1.0 + (double)(p & M44) * (1.0 / 4294967296.0));
    dis[i] = rsqrtf(dg);
    cnt[i] = c;
}

// k_gather: r5-PROVEN SHAPE (one node per 16-lane group, max TLP -- r7 lesson:
// do NOT shrink the grid of a latency-bound gather). Lane j prefetches record
// e+j AND its dis[col] (random 4B, L2-resident 400KB), pre-multiplies the
// weight, then 16 shuffle-broadcast independent x-row loads.
// out_i = dis_i * (dis_i * x_i + sum w*dis_col*x[col]).  Writes agg = d_out.
__global__ __launch_bounds__(256) void k_gather(const float* __restrict__ x,
                                                const float* __restrict__ dis,
                                                const int* __restrict__ cnt,
                                                const unsigned int* __restrict__ slots,
                                                float* __restrict__ agg, int n) {
    int g = blockIdx.x * 256 + threadIdx.x;
    int i = g >> 4;
    if (i >= n) return;
    int j = g & 15;

    const float4* x4 = (const float4*)x;
    float4 acc = make_float4(0.f, 0.f, 0.f, 0.f);
    int c_n = cnt[i];
    int s = i * K;
    for (int off = 0; off < c_n; off += 16) {
        int idx = off + j;
        unsigned int rec = 0u;
        float wj = 0.f;
        if (idx < c_n) {
            rec = slots[s + idx];
            wj = (float)(rec & 32767u) * (1.0f / 32768.0f) * dis[rec >> 15];
        }
        int mm = c_n - off; if (mm > 16) mm = 16;
#pragma unroll
        for (int t = 0; t < 16; ++t) {
            if (t < mm) {
                int col = (int)((unsigned int)__shfl((int)rec, t, 16) >> 15);
                float w = __shfl(wj, t, 16);
                float4 xv = x4[col * 16 + j];
                acc.x += w * xv.x; acc.y += w * xv.y;
                acc.z += w * xv.z; acc.w += w * xv.w;
            }
        }
    }
    float di = dis[i];
    float4 xi = x4[i * 16 + j];
    float4 o;
    o.x = di * (di * xi.x + acc.x);
    o.y = di * (di * xi.y + acc.y);
    o.z = di * (di * xi.z + acc.z);
    o.w = di * (di * xi.w + acc.w);
    ((float4*)agg)[i * 16 + j] = o;
}

// k_spill: rare overflow edges (expected 0). One thread per spill edge,
// 64 float atomicAdds into agg. Runs between gather and gemm.
__global__ __launch_bounds__(256) void k_spill(const int4* __restrict__ spill,
                                               const int* __restrict__ spillCnt,
                                               const float* __restrict__ x,
                                               const float* __restrict__ dis,
                                               float* __restrict__ agg) {
    int total = *spillCnt;
    if (total > SPILLCAP) total = SPILLCAP;
    for (int s = blockIdx.x * 256 + threadIdx.x; s < total; s += gridDim.x * 256) {
        int4 v = spill[s];
        float norm = dis[v.x] * __int_as_float(v.z) * dis[v.y];
        const float* xc = x + (size_t)v.y * D;
        float* ar = agg + (size_t)v.x * D;
        for (int k = 0; k < D; ++k) atomicAdd(&ar[k], norm * xc[k]);
    }
}

// gcn_gemm: r5-PROVEN. Swizzled LDS (zero padding, bank floor), 4x4 register
// tile, launch_bounds(256,4) caps VGPR (r4 lesson). In-place safe: block
// stages its 64 rows to LDS before overwriting them.
__global__ __launch_bounds__(256, 4) void gcn_gemm(const float* __restrict__ agg,
                                                   const float* __restrict__ W,
                                                   const float* __restrict__ bias,
                                                   float* __restrict__ out, int n) {
    __shared__ float Ast[D * D];
    __shared__ float Bs[D * D];
    float4* Ast4 = (float4*)Ast;
    int tid = threadIdx.x;
    int r0 = blockIdx.x * 64;

    const float4* W4 = (const float4*)W;
    const float4* A4 = (const float4*)agg;
#pragma unroll
    for (int v = 0; v < 4; ++v) {
        int idx = tid + v * 256;
        int a  = idx >> 4;
        int kc = idx & 15;
        int ra = r0 + a;
        float4 av = make_float4(0.f, 0.f, 0.f, 0.f);
        if (ra < n) av = A4[ra * 16 + kc];
        Ast4[a * 16 + ((kc + (a >> 2)) & 15)] = av;
        float4 wv = W4[idx];
        int gq = a >> 2, oo = a & 3;
        { int k = 4 * kc + 0; Bs[k * 64 + 4 * ((gq + k) & 15) + oo] = wv.x; }
        { int k = 4 * kc + 1; Bs[k * 64 + 4 * ((gq + k) & 15) + oo] = wv.y; }
        { int k = 4 * kc + 2; Bs[k * 64 + 4 * ((gq + k) & 15) + oo] = wv.z; }
        { int k = 4 * kc + 3; Bs[k * 64 + 4 * ((gq + k) & 15) + oo] = wv.w; }
    }
    __syncthreads();

    int ty = tid >> 4;
    int tx = tid & 15;
    float acc[4][4];
#pragma unroll
    for (int m = 0; m < 4; ++m)
#pragma unroll
        for (int q = 0; q < 4; ++q) acc[m][q] = 0.f;

#pragma unroll 4
    for (int kc = 0; kc < 16; ++kc) {
        float4 a4[4], b4[4];
#pragma unroll
        for (int m = 0; m < 4; ++m)
            a4[m] = Ast4[(4 * ty + m) * 16 + ((kc + ty) & 15)];
#pragma unroll
        for (int i = 0; i < 4; ++i) {
            int k = 4 * kc + i;
            b4[i] = *(const float4*)&Bs[k * 64 + 4 * ((tx + k) & 15)];
        }
#pragma unroll
        for (int m = 0; m < 4; ++m) {
            acc[m][0] += a4[m].x * b4[0].x + a4[m].y * b4[1].x + a4[m].z * b4[2].x + a4[m].w * b4[3].x;
            acc[m][1] += a4[m].x * b4[0].y + a4[m].y * b4[1].y + a4[m].z * b4[2].y + a4[m].w * b4[3].y;
            acc[m][2] += a4[m].x * b4[0].z + a4[m].y * b4[1].z + a4[m].z * b4[2].z + a4[m].w * b4[3].z;
            acc[m][3] += a4[m].x * b4[0].w + a4[m].y * b4[1].w + a4[m].z * b4[2].w + a4[m].w * b4[3].w;
        }
    }

    float4 bv = ((const float4*)bias)[tx];
    float4* out4 = (float4*)out;
#pragma unroll
    for (int m = 0; m < 4; ++m) {
        int r = r0 + 4 * ty + m;
        if (r < n) {
            float4 o;
            o.x = acc[m][0] + bv.x; o.y = acc[m][1] + bv.y;
            o.z = acc[m][2] + bv.z; o.w = acc[m][3] + bv.w;
            out4[r * 16 + tx] = o;
        }
    }
}

extern "C" void kernel_launch(void* const* d_in, const int* in_sizes, int n_in,
                              void* d_out, int out_size, void* d_ws, size_t ws_size,
                              hipStream_t stream) {
    const float* x    = (const float*)d_in[0];
    const int*   ei   = (const int*)d_in[1];   // [2*E] flat: rows then cols
    const float* ew   = (const float*)d_in[2];
    const float* W    = (const float*)d_in[3];
    const float* bias = (const float*)d_in[4];
    float* out = (float*)d_out;

    int n  = in_sizes[0] / D;   // 100000
    int nE = in_sizes[2];       // 1000000
    const int* rowi = ei;
    const int* coli = ei + nE;

    // workspace (~15.4 MB): packed | spillCnt | slots | dis | cnt | spill
    char* w = (char*)d_ws;
    unsigned long long* packed = (unsigned long long*)w; w += (size_t)n * 8;
    int* spillCnt = (int*)w;                             w += 64;
    unsigned int* slots = (unsigned int*)w;              w += (size_t)n * K * 4;
    float* dis = (float*)w;                              w += (size_t)n * 4;
    int*   cnt = (int*)w;                                w += (size_t)n * 4;
    int4*  spill = (int4*)w;

    int gn  = (n + 255) / 256;
    int gE  = (nE + 255) / 256;
    int gNd = (n * 16 + 255) / 256;

    hipMemsetAsync(packed, 0, (size_t)n * 8 + 64, stream);   // packed + spillCnt
    k_build <<<gE, 256, 0, stream>>>(rowi, coli, ew, packed, slots, spill, spillCnt, nE);
    k_dis   <<<gn, 256, 0, stream>>>(packed, dis, cnt, n);
    k_gather<<<gNd, 256, 0, stream>>>(x, dis, cnt, slots, out, n);
    k_spill <<<16, 256, 0, stream>>>(spill, spillCnt, x, dis, out);
    gcn_gemm<<<(n + 63) / 64, 256, 0, stream>>>(out, W, bias, out, n);
}